// Round 3
// baseline (373.198 us; speedup 1.0000x reference)
//
#include <hip/hip_runtime.h>
#include <math.h>

#define B_    16
#define M_    8
#define T_    250
#define L_    1024
#define NPAIR 28

#define CH_K   128      // halfs per chunk (64 bins)
#define NKT    4
#define NCHUNK 8
#define APITCH 136      // halfs: 272 B row pitch (16B-aligned, not a 128B multiple)
#define ABUF   (32 * APITCH)   // halfs per A buffer

typedef _Float16 half8  __attribute__((ext_vector_type(8)));
typedef _Float16 half2t __attribute__((ext_vector_type(2)));
typedef float    floatx4 __attribute__((ext_vector_type(4)));

__device__ __align__(16) _Float16 g_Btw[64 * 1024];

// np.triu_indices(8, k=1) — used only by the (rare) Nyquist fixup
__constant__ int c_i1[NPAIR] = {0,0,0,0,0,0,0,1,1,1,1,1,1,2,2,2,2,2,3,3,3,3,4,4,4,5,5,6};
__constant__ int c_i2[NPAIR] = {1,2,3,4,5,6,7,2,3,4,5,6,7,3,4,5,6,7,4,5,6,7,5,6,7,6,7,7};

// B[n][k]: k=0 -> DC (1/1024); k=1 -> Nyquist slot ((-1)^n/1024); k=2b -> 2cos/1024, 2b+1 -> -2sin/1024
__global__ void init_btw() {
    int idx = blockIdx.x * 256 + threadIdx.x;
    int n = idx >> 10, k = idx & 1023;
    float v;
    if (k == 0)      v = 1.0f / 1024.0f;
    else if (k == 1) v = (n & 1) ? (-1.0f / 1024.0f) : (1.0f / 1024.0f);
    else {
        int bin = k >> 1, tau = n - 32;
        int r = (tau * bin) & 1023;
        float ang = (float)r * (6.283185307179586f / 1024.0f);
        float s, c; sincosf(ang, &s, &c);
        v = ((k & 1) ? -s : c) * (2.0f / 1024.0f);
    }
    g_Btw[idx] = (_Float16)v;
}

// Bijective XOR swizzle (no padding): bits0-3 ^= bits4-7, bits1-2 ^= bits8-9.
// Conflict-floor for strides 512/64/8/1 and the posmap gather. s_z = 32 KiB exact.
#define PHI(i) ((i) ^ (((i) >> 4) & 15) ^ ((((i) >> 8) & 3) << 1))

__device__ inline float2 cmul(float2 a, float2 b) {
    return make_float2(fmaf(a.x, b.x, -a.y * b.y), fmaf(a.x, b.y, a.y * b.x));
}
__device__ inline float2 cadd(float2 a, float2 b) { return make_float2(a.x + b.x, a.y + b.y); }
__device__ inline float2 csub(float2 a, float2 b) { return make_float2(a.x - b.x, a.y - b.y); }
__device__ inline float2 cmni(float2 a) { return make_float2(a.y, -a.x); }  // a * (-i)

// DIF 8-point DFT: y_k = sum_r v_r W8^{rk}, in place
__device__ inline void dft8(float2 v[8]) {
    const float rt = 0.70710678118654752440f;
    float2 b0 = cadd(v[0], v[4]), b1 = cadd(v[1], v[5]);
    float2 b2 = cadd(v[2], v[6]), b3 = cadd(v[3], v[7]);
    float2 c0 = csub(v[0], v[4]);
    float2 t1 = csub(v[1], v[5]);
    float2 c1 = make_float2(rt * (t1.x + t1.y), rt * (t1.y - t1.x));   // *W8^1
    float2 c2 = cmni(csub(v[2], v[6]));                                 // *W8^2
    float2 t3 = csub(v[3], v[7]);
    float2 c3 = make_float2(rt * (t3.y - t3.x), -rt * (t3.x + t3.y));  // *W8^3
    float2 f0 = cadd(b0, b2), f1 = cadd(b1, b3);
    float2 g0 = csub(b0, b2), g1 = cmni(csub(b1, b3));
    v[0] = cadd(f0, f1); v[4] = csub(f0, f1);
    v[2] = cadd(g0, g1); v[6] = csub(g0, g1);
    f0 = cadd(c0, c2); f1 = cadd(c1, c3);
    g0 = csub(c0, c2); g1 = cmni(csub(c1, c3));
    v[1] = cadd(f0, f1); v[5] = csub(f0, f1);
    v[3] = cadd(g0, g1); v[7] = csub(g0, g1);
}

__device__ inline void twiddle8(float2 v[8], float2 w1) {
    float2 w = w1;
    v[1] = cmul(v[1], w);
#pragma unroll
    for (int k = 2; k < 8; ++k) { w = cmul(w, w1); v[k] = cmul(v[k], w); }
}

// DIF radices (2,8,8,8): X[k] sits at p(k)
__device__ inline int posmap(int k) {
    return ((k & 1) << 9) | (((k >> 1) & 7) << 6) | (((k >> 4) & 7) << 3) | ((k >> 7) & 7);
}

__global__ __launch_bounds__(512, 4) void gcc_main(const float* __restrict__ x,
                                                   float* __restrict__ out) {
    __shared__ float2 s_z[4 * 1024];                                  // 32768 B
    __shared__ __align__(16) _Float16 sA[2 * ABUF];                   // 17408 B (dbuf)
    // total 50176 B -> 3 blocks/CU (163840/50176), same as best round 0

    const int tid = threadIdx.x;
    const int t = blockIdx.x, b = blockIdx.y;
    const int f = tid & 127, c = tid >> 7;
    float2* Zb = s_z + c * 1024;

    // per-thread base twiddle w = W_1024^f
    float ws, wc;
    sincosf((float)f * (-6.283185307179586f / 1024.0f), &ws, &wc);
    const float2 w = make_float2(wc, ws);

    // ---- fused global load + radix-2 stage (stride 512) ----
    {
        const float* xa = x + (((size_t)b * M_ + 2 * c) * T_ + t) * L_;
        const float* xb = xa + (size_t)T_ * L_;
        float va[8], vb[8];
#pragma unroll
        for (int j = 0; j < 8; ++j) { va[j] = xa[f + 128 * j]; vb[j] = xb[f + 128 * j]; }
        const float rt = 0.70710678118654752440f;
#pragma unroll
        for (int q = 0; q < 4; ++q) {
            float2 a = make_float2(va[q], vb[q]);
            float2 d = make_float2(va[q + 4], vb[q + 4]);
            float2 tq = cmul(csub(a, d), w);
            float2 r;
            if (q == 0)      r = tq;                                            // *1
            else if (q == 1) r = make_float2(rt * (tq.x + tq.y), rt * (tq.y - tq.x));   // *W8^1
            else if (q == 2) r = make_float2(tq.y, -tq.x);                      // *W8^2
            else             r = make_float2(rt * (tq.y - tq.x), -rt * (tq.x + tq.y)); // *W8^3
            Zb[PHI(f + 128 * q)]       = cadd(a, d);
            Zb[PHI(f + 128 * q + 512)] = r;
        }
    }
    __syncthreads();

    // ---- Stage B: radix-8, stride 64 ----
    {
        float2 wl = w;
        if (f & 64) wl = cmul(wl, make_float2(0.92387953251128674f, 0.38268343236508977f));
        const float2 wB = cmul(wl, wl);
        const int base = (f >> 6) * 512 + (f & 63);
        float2 v[8];
#pragma unroll
        for (int r = 0; r < 8; ++r) v[r] = Zb[PHI(base + 64 * r)];
        dft8(v);
        twiddle8(v, wB);
#pragma unroll
        for (int k = 0; k < 8; ++k) Zb[PHI(base + 64 * k)] = v[k];
    }
    __syncthreads();

    // ---- Stage C: radix-8, stride 8 ----
    {
        float s2, c2;
        sincosf((float)(f & 7) * (-6.283185307179586f / 64.0f), &s2, &c2);
        const float2 wC = make_float2(c2, s2);
        const int base = (f >> 3) * 64 + (f & 7);
        float2 v[8];
#pragma unroll
        for (int r = 0; r < 8; ++r) v[r] = Zb[PHI(base + 8 * r)];
        dft8(v);
        twiddle8(v, wC);
#pragma unroll
        for (int k = 0; k < 8; ++k) Zb[PHI(base + 8 * k)] = v[k];
    }
    __syncthreads();

    // ---- Stage D: radix-8, stride 1 (no twiddle) ----
    {
        const int base = f * 8;
        float2 v[8];
#pragma unroll
        for (int r = 0; r < 8; ++r) v[r] = Zb[PHI(base + r)];
        dft8(v);
#pragma unroll
        for (int k = 0; k < 8; ++k) Zb[PHI(base + k)] = v[k];
    }
    __syncthreads();

    // ---- back half: dbuf A, 1 barrier/chunk, fill(h+1) overlaps mma(h) ----
    const int lane = tid & 63, wv = tid >> 6;
    const int mt = wv >> 2, nt = wv & 3;
    const int l15 = lane & 15, quad = lane >> 4;
    const int arow = mt * 16 + l15;
    const _Float16* Bbase = g_Btw + (size_t)(nt * 16 + l15) * 1024 + quad * 8;
    floatx4 acc = {0.0f, 0.0f, 0.0f, 0.0f};

    const int bl = lane;   // bin-local 0..63
    const int pg = wv;     // pair-group 0..7 (wave-uniform)

    // COMPILE-TIME pair indices only — dynamic indexing of Xs forces scratch.
#define PAIRA(p_, a_, b_)                                                     \
    {                                                                         \
        float2 X1 = Xs[a_], X2 = Xs[b_];                                      \
        float rr = X1.x * X2.x + X1.y * X2.y;                                 \
        float ri = X1.y * X2.x - X1.x * X2.y;                                 \
        float m2 = rr * rr + ri * ri;                                         \
        float inv = (m2 > 1e-30f) ? rsqrtf(m2) : 0.0f;                        \
        *(half2t*)&dst[(p_) * APITCH + 2 * bl] =                              \
            (half2t){(_Float16)(rr * inv), (_Float16)(ri * inv)};             \
    }

    auto fillA = [&](int h, _Float16* dst) {
        const int beta = h * 64 + bl;
        const int pa = posmap(beta);
        const int pb = posmap((1024 - beta) & 1023);
        float2 Xs[8];
#pragma unroll
        for (int cc = 0; cc < 4; ++cc) {
            float2 Aa = s_z[cc * 1024 + PHI(pa)];
            float2 Bb = s_z[cc * 1024 + PHI(pb)];
            Xs[2 * cc]     = make_float2(0.5f * (Aa.x + Bb.x), 0.5f * (Aa.y - Bb.y));
            Xs[2 * cc + 1] = make_float2(0.5f * (Aa.y + Bb.y), 0.5f * (Bb.x - Aa.x));
        }
        if (pg == 0) {
            PAIRA(0, 0, 1) PAIRA(1, 0, 2) PAIRA(2, 0, 3) PAIRA(3, 0, 4)
        } else if (pg == 1) {
            PAIRA(4, 0, 5) PAIRA(5, 0, 6) PAIRA(6, 0, 7) PAIRA(7, 1, 2)
        } else if (pg == 2) {
            PAIRA(8, 1, 3) PAIRA(9, 1, 4) PAIRA(10, 1, 5) PAIRA(11, 1, 6)
        } else if (pg == 3) {
            PAIRA(12, 1, 7) PAIRA(13, 2, 3) PAIRA(14, 2, 4) PAIRA(15, 2, 5)
        } else if (pg == 4) {
            PAIRA(16, 2, 6) PAIRA(17, 2, 7) PAIRA(18, 3, 4)
        } else if (pg == 5) {
            PAIRA(19, 3, 5) PAIRA(20, 3, 6) PAIRA(21, 3, 7)
        } else if (pg == 6) {
            PAIRA(22, 4, 5) PAIRA(23, 4, 6) PAIRA(24, 4, 7)
        } else {
            PAIRA(25, 5, 6) PAIRA(26, 5, 7) PAIRA(27, 6, 7)
        }
        if (h == 0 && bl == 0) {               // Nyquist -> hijacked col k=1
            const int p0 = (pg < 4) ? 4 * pg : 16 + 3 * (pg - 4);
            const int cnt = (pg < 4) ? 4 : 3;
            const int pN = 4;                  // PHI(posmap(512)) == 4
#pragma unroll
            for (int pp = 0; pp < cnt; ++pp) {
                const int p = p0 + pp;
                float2 Za = s_z[(c_i1[p] >> 1) * 1024 + pN];
                float2 Zc = s_z[(c_i2[p] >> 1) * 1024 + pN];
                float x1 = (c_i1[p] & 1) ? Za.y : Za.x;
                float x2 = (c_i2[p] & 1) ? Zc.y : Zc.x;
                float rr = x1 * x2;
                float inv = (rr * rr > 1e-30f) ? rsqrtf(rr * rr) : 0.0f;
                dst[p * APITCH + 1] = (_Float16)(rr * inv);
            }
        }
    };

    // B prefetch for chunk 0 (hides g_Btw latency under fill0)
    half8 bc[4], bn[4];
#pragma unroll
    for (int kt = 0; kt < NKT; ++kt) bc[kt] = *(const half8*)(Bbase + kt * 32);

    fillA(0, sA);
    __syncthreads();

#pragma unroll
    for (int h = 0; h < NCHUNK; ++h) {
        if (h < NCHUNK - 1) {
            const _Float16* Bn = Bbase + (h + 1) * CH_K;
#pragma unroll
            for (int kt = 0; kt < NKT; ++kt) bn[kt] = *(const half8*)(Bn + kt * 32);
            fillA(h + 1, sA + ((h + 1) & 1) * ABUF);   // writes buf (h+1)&1
        }
        const _Float16* Ap = sA + (h & 1) * ABUF + arow * APITCH;   // reads buf h&1
#pragma unroll
        for (int kt = 0; kt < NKT; ++kt) {
            half8 af = *(const half8*)(Ap + kt * 32 + quad * 8);
            acc = __builtin_amdgcn_mfma_f32_16x16x32_f16(af, bc[kt], acc, 0, 0, 0);
        }
#pragma unroll
        for (int kt = 0; kt < NKT; ++kt) bc[kt] = bn[kt];
        if (h < NCHUNK - 1) __syncthreads();
    }

    // ---- Epilogue: C/D layout col=lane&15, row=quad*4+reg ----
#pragma unroll
    for (int r = 0; r < 4; ++r) {
        int pair = mt * 16 + quad * 4 + r;
        if (pair < NPAIR)
            out[((((size_t)b * NPAIR + pair) * T_ + t) << 6) + nt * 16 + l15] = acc[r];
    }
}

extern "C" void kernel_launch(void* const* d_in, const int* in_sizes, int n_in,
                              void* d_out, int out_size, void* d_ws, size_t ws_size,
                              hipStream_t stream) {
    (void)in_sizes; (void)n_in; (void)d_ws; (void)ws_size; (void)out_size;
    hipLaunchKernelGGL(init_btw, dim3(256), dim3(256), 0, stream);
    hipLaunchKernelGGL(gcc_main, dim3(T_, B_), dim3(512), 0, stream,
                       (const float*)d_in[0], (float*)d_out);
}

// Round 4
// 296.580 us; speedup vs baseline: 1.2583x; 1.2583x over previous
//
#include <hip/hip_runtime.h>
#include <math.h>

#define B_    16
#define M_    8
#define T_    250
#define L_    1024
#define NPAIR 28

#define KTOT   1024
#define CH_K   256      // halfs per chunk (128 bins)
#define NKT    8
#define NCHUNK 4
#define APITCH 264      // 256 + 8 halfs pad; row stride 528 B (16B multiple)

typedef _Float16 half8  __attribute__((ext_vector_type(8)));
typedef _Float16 half2t __attribute__((ext_vector_type(2)));
typedef float    floatx4 __attribute__((ext_vector_type(4)));

__device__ __align__(16) _Float16 g_Btw[64 * KTOT];

// np.triu_indices(8, k=1) — used only by the (rare) Nyquist fixup
__constant__ int c_i1[NPAIR] = {0,0,0,0,0,0,0,1,1,1,1,1,1,2,2,2,2,2,3,3,3,3,4,4,4,5,5,6};
__constant__ int c_i2[NPAIR] = {1,2,3,4,5,6,7,2,3,4,5,6,7,3,4,5,6,7,4,5,6,7,5,6,7,6,7,7};

// B[n][k]: k=0 -> DC (1/1024); k=1 -> Nyquist slot ((-1)^n/1024); k=2b -> 2cos/1024, 2b+1 -> -2sin/1024
__global__ void init_btw() {
    int idx = blockIdx.x * 256 + threadIdx.x;
    int n = idx >> 10, k = idx & 1023;
    float v;
    if (k == 0)      v = 1.0f / 1024.0f;
    else if (k == 1) v = (n & 1) ? (-1.0f / 1024.0f) : (1.0f / 1024.0f);
    else {
        int bin = k >> 1, tau = n - 32;
        int r = (tau * bin) & 1023;
        float ang = (float)r * (6.283185307179586f / 1024.0f);
        float s, c; sincosf(ang, &s, &c);
        v = ((k & 1) ? -s : c) * (2.0f / 1024.0f);
    }
    g_Btw[idx] = (_Float16)v;
}

// Bijective XOR swizzle (no padding): bits0-3 ^= bits4-7, bits1-2 ^= bits8-9.
// Verified rounds 1-3 (absmax identical); s_z = exactly 32 KiB.
#define PHI(i) ((i) ^ (((i) >> 4) & 15) ^ ((((i) >> 8) & 3) << 1))

__device__ inline float2 cmul(float2 a, float2 b) {
    return make_float2(fmaf(a.x, b.x, -a.y * b.y), fmaf(a.x, b.y, a.y * b.x));
}
__device__ inline float2 cadd(float2 a, float2 b) { return make_float2(a.x + b.x, a.y + b.y); }
__device__ inline float2 csub(float2 a, float2 b) { return make_float2(a.x - b.x, a.y - b.y); }
__device__ inline float2 cmni(float2 a) { return make_float2(a.y, -a.x); }  // a * (-i)

// DIF 8-point DFT: y_k = sum_r v_r W8^{rk}, in place
__device__ inline void dft8(float2 v[8]) {
    const float rt = 0.70710678118654752440f;
    float2 b0 = cadd(v[0], v[4]), b1 = cadd(v[1], v[5]);
    float2 b2 = cadd(v[2], v[6]), b3 = cadd(v[3], v[7]);
    float2 c0 = csub(v[0], v[4]);
    float2 t1 = csub(v[1], v[5]);
    float2 c1 = make_float2(rt * (t1.x + t1.y), rt * (t1.y - t1.x));   // *W8^1
    float2 c2 = cmni(csub(v[2], v[6]));                                 // *W8^2
    float2 t3 = csub(v[3], v[7]);
    float2 c3 = make_float2(rt * (t3.y - t3.x), -rt * (t3.x + t3.y));  // *W8^3
    float2 f0 = cadd(b0, b2), f1 = cadd(b1, b3);
    float2 g0 = csub(b0, b2), g1 = cmni(csub(b1, b3));
    v[0] = cadd(f0, f1); v[4] = csub(f0, f1);
    v[2] = cadd(g0, g1); v[6] = csub(g0, g1);
    f0 = cadd(c0, c2); f1 = cadd(c1, c3);
    g0 = csub(c0, c2); g1 = cmni(csub(c1, c3));
    v[1] = cadd(f0, f1); v[5] = csub(f0, f1);
    v[3] = cadd(g0, g1); v[7] = csub(g0, g1);
}

// twiddle powers as a depth-3 tree (was a serial 6-deep cmul recurrence)
__device__ inline void twiddle8(float2 v[8], float2 w1) {
    float2 w2 = cmul(w1, w1);
    float2 w3 = cmul(w2, w1);
    float2 w4 = cmul(w2, w2);
    float2 w5 = cmul(w4, w1);
    float2 w6 = cmul(w4, w2);
    float2 w7 = cmul(w4, w3);
    v[1] = cmul(v[1], w1); v[2] = cmul(v[2], w2); v[3] = cmul(v[3], w3);
    v[4] = cmul(v[4], w4); v[5] = cmul(v[5], w5); v[6] = cmul(v[6], w6);
    v[7] = cmul(v[7], w7);
}

// DIF radices (2,8,8,8): X[k] sits at p(k)
__device__ inline int posmap(int k) {
    return ((k & 1) << 9) | (((k >> 1) & 7) << 6) | (((k >> 4) & 7) << 3) | ((k >> 7) & 7);
}

__global__ __launch_bounds__(512, 4) void gcc_main(const float* __restrict__ x,
                                                   float* __restrict__ out) {
    __shared__ float2 s_z[4 * 1024];                                  // 32768 B
    __shared__ __align__(16) _Float16 sA[32 * APITCH];                // 16896 B
    // total 49664 B -> 3 blocks/CU (round-0-proven occupancy)

    const int tid = threadIdx.x;
    const int t = blockIdx.x, b = blockIdx.y;
    const int f = tid & 127, c = tid >> 7;
    float2* Zb = s_z + c * 1024;

    // per-thread base twiddle w = W_1024^f (no lut table)
    float ws, wc;
    sincosf((float)f * (-6.283185307179586f / 1024.0f), &ws, &wc);
    const float2 w = make_float2(wc, ws);

    // ---- fused global load + radix-2 stage (stride 512): saves 1 barrier + 1 LDS pass ----
    {
        const float* xa = x + (((size_t)b * M_ + 2 * c) * T_ + t) * L_;
        const float* xb = xa + (size_t)T_ * L_;
        float va[8], vb[8];
#pragma unroll
        for (int j = 0; j < 8; ++j) { va[j] = xa[f + 128 * j]; vb[j] = xb[f + 128 * j]; }
        const float rt = 0.70710678118654752440f;
#pragma unroll
        for (int q = 0; q < 4; ++q) {
            float2 a = make_float2(va[q], vb[q]);
            float2 d = make_float2(va[q + 4], vb[q + 4]);
            float2 tq = cmul(csub(a, d), w);
            float2 r;
            if (q == 0)      r = tq;                                            // *W8^0
            else if (q == 1) r = make_float2(rt * (tq.x + tq.y), rt * (tq.y - tq.x));   // *W8^1
            else if (q == 2) r = make_float2(tq.y, -tq.x);                      // *W8^2
            else             r = make_float2(rt * (tq.y - tq.x), -rt * (tq.x + tq.y)); // *W8^3
            Zb[PHI(f + 128 * q)]       = cadd(a, d);
            Zb[PHI(f + 128 * q + 512)] = r;
        }
    }
    __syncthreads();

    // ---- Stage B: radix-8, stride 64 ----
    {
        float2 wl = w;
        if (f & 64) wl = cmul(wl, make_float2(0.92387953251128674f, 0.38268343236508977f));
        const float2 wB = cmul(wl, wl);   // = W_1024^{2*(f&63)}
        const int base = (f >> 6) * 512 + (f & 63);
        float2 v[8];
#pragma unroll
        for (int r = 0; r < 8; ++r) v[r] = Zb[PHI(base + 64 * r)];
        dft8(v);
        twiddle8(v, wB);
#pragma unroll
        for (int k = 0; k < 8; ++k) Zb[PHI(base + 64 * k)] = v[k];
    }
    __syncthreads();

    // ---- Stage C: radix-8, stride 8 ----
    {
        float s2, c2;
        sincosf((float)(f & 7) * (-6.283185307179586f / 64.0f), &s2, &c2);  // W_1024^{16*(f&7)}
        const float2 wC = make_float2(c2, s2);
        const int base = (f >> 3) * 64 + (f & 7);
        float2 v[8];
#pragma unroll
        for (int r = 0; r < 8; ++r) v[r] = Zb[PHI(base + 8 * r)];
        dft8(v);
        twiddle8(v, wC);
#pragma unroll
        for (int k = 0; k < 8; ++k) Zb[PHI(base + 8 * k)] = v[k];
    }
    __syncthreads();

    // ---- Stage D: radix-8, stride 1 (no twiddle) ----
    {
        const int base = f * 8;
        float2 v[8];
#pragma unroll
        for (int r = 0; r < 8; ++r) v[r] = Zb[PHI(base + r)];
        dft8(v);
#pragma unroll
        for (int k = 0; k < 8; ++k) Zb[PHI(base + k)] = v[k];
    }
    __syncthreads();

    // ---- Phases 2+3: round-0 structure verbatim (4 chunks of 128 bins) ----
    const int lane = tid & 63, wv = tid >> 6;
    const int mt = wv >> 2, nt = wv & 3;
    const int l15 = lane & 15, quad = lane >> 4;
    const int arow = mt * 16 + l15;
    const _Float16* Bbase = g_Btw + (nt * 16 + l15) * KTOT;
    floatx4 acc = {0.0f, 0.0f, 0.0f, 0.0f};

    const int bl = tid & 127, pg = tid >> 7;   // A-fill: (bin-local, pair-group of 7)

    // COMPILE-TIME pair indices only — dynamic indexing of Xs forces scratch.
#define PAIRA(p_, a_, b_)                                                     \
    {                                                                         \
        float2 X1 = Xs[a_], X2 = Xs[b_];                                      \
        float rr = X1.x * X2.x + X1.y * X2.y;                                 \
        float ri = X1.y * X2.x - X1.x * X2.y;                                 \
        float m2 = rr * rr + ri * ri;                                         \
        float inv = (m2 > 1e-30f) ? rsqrtf(m2) : 0.0f;                        \
        *(half2t*)&sA[(p_) * APITCH + 2 * bl] =                               \
            (half2t){(_Float16)(rr * inv), (_Float16)(ri * inv)};             \
    }

    auto fillA = [&](int h) {
        const int beta = h * 128 + bl;
        const int pa = posmap(beta);
        const int pb = posmap((1024 - beta) & 1023);
        float2 Xs[8];
#pragma unroll
        for (int cc = 0; cc < 4; ++cc) {
            float2 Aa = s_z[cc * 1024 + PHI(pa)];
            float2 Bb = s_z[cc * 1024 + PHI(pb)];
            Xs[2 * cc]     = make_float2(0.5f * (Aa.x + Bb.x), 0.5f * (Aa.y - Bb.y));
            Xs[2 * cc + 1] = make_float2(0.5f * (Aa.y + Bb.y), 0.5f * (Bb.x - Aa.x));
        }
        // pg is wave-uniform (tid>>7): 4-way uniform branch, literal indices
        if (pg == 0) {
            PAIRA(0, 0, 1) PAIRA(1, 0, 2) PAIRA(2, 0, 3) PAIRA(3, 0, 4)
            PAIRA(4, 0, 5) PAIRA(5, 0, 6) PAIRA(6, 0, 7)
        } else if (pg == 1) {
            PAIRA(7, 1, 2) PAIRA(8, 1, 3) PAIRA(9, 1, 4) PAIRA(10, 1, 5)
            PAIRA(11, 1, 6) PAIRA(12, 1, 7) PAIRA(13, 2, 3)
        } else if (pg == 2) {
            PAIRA(14, 2, 4) PAIRA(15, 2, 5) PAIRA(16, 2, 6) PAIRA(17, 2, 7)
            PAIRA(18, 3, 4) PAIRA(19, 3, 5) PAIRA(20, 3, 6)
        } else {
            PAIRA(21, 3, 7) PAIRA(22, 4, 5) PAIRA(23, 4, 6) PAIRA(24, 4, 7)
            PAIRA(25, 5, 6) PAIRA(26, 5, 7) PAIRA(27, 6, 7)
        }
        if (h == 0 && bl == 0) {               // Nyquist -> hijacked col k=1 (LDS reads only)
            const int pN = 4;                  // PHI(posmap(512)) == 4
#pragma unroll
            for (int pp = 0; pp < 7; ++pp) {
                const int p = pg * 7 + pp;
                float2 Za = s_z[(c_i1[p] >> 1) * 1024 + pN];
                float2 Zc = s_z[(c_i2[p] >> 1) * 1024 + pN];
                float x1 = (c_i1[p] & 1) ? Za.y : Za.x;
                float x2 = (c_i2[p] & 1) ? Zc.y : Zc.x;
                float rr = x1 * x2;
                float inv = (rr * rr > 1e-30f) ? rsqrtf(rr * rr) : 0.0f;
                sA[p * APITCH + 1] = (_Float16)(rr * inv);
            }
        }
    };

    for (int h = 0; h < NCHUNK; ++h) {
        fillA(h);
        __syncthreads();

        const _Float16* Ap = sA + arow * APITCH;
        const _Float16* Bp = Bbase + h * CH_K;
#pragma unroll
        for (int kt = 0; kt < NKT; ++kt) {
            half8 af = *(const half8*)(Ap + kt * 32 + quad * 8);
            half8 bf = *(const half8*)(Bp + kt * 32 + quad * 8);
            acc = __builtin_amdgcn_mfma_f32_16x16x32_f16(af, bf, acc, 0, 0, 0);
        }
        __syncthreads();
    }

    // ---- Epilogue: C/D layout col=lane&15, row=quad*4+reg ----
#pragma unroll
    for (int r = 0; r < 4; ++r) {
        int pair = mt * 16 + quad * 4 + r;
        if (pair < NPAIR)
            out[((((size_t)b * NPAIR + pair) * T_ + t) << 6) + nt * 16 + l15] = acc[r];
    }
}

extern "C" void kernel_launch(void* const* d_in, const int* in_sizes, int n_in,
                              void* d_out, int out_size, void* d_ws, size_t ws_size,
                              hipStream_t stream) {
    (void)in_sizes; (void)n_in; (void)d_ws; (void)ws_size; (void)out_size;
    hipLaunchKernelGGL(init_btw, dim3(256), dim3(256), 0, stream);
    hipLaunchKernelGGL(gcc_main, dim3(T_, B_), dim3(512), 0, stream,
                       (const float*)d_in[0], (float*)d_out);
}

// Round 5
// 288.292 us; speedup vs baseline: 1.2945x; 1.0287x over previous
//
#include <hip/hip_runtime.h>
#include <math.h>

#define B_    16
#define M_    8
#define T_    250
#define L_    1024
#define NPAIR 28

#define KTOT   1024
#define CH_K   256      // halfs per chunk (128 bins)
#define NKT    8
#define NCHUNK 4
#define APITCH 264      // 256 + 8 halfs pad; row stride 528 B (16B multiple)
#define XPLANE (516 * 8)   // halfs per fp16-spectrum plane (8256 B)

typedef _Float16 half8  __attribute__((ext_vector_type(8)));
typedef _Float16 half2t __attribute__((ext_vector_type(2)));
typedef float    floatx4 __attribute__((ext_vector_type(4)));

__device__ __align__(16) _Float16 g_Btw[64 * KTOT];

// np.triu_indices(8, k=1) — used only by the Nyquist fixup
__constant__ int c_i1[NPAIR] = {0,0,0,0,0,0,0,1,1,1,1,1,1,2,2,2,2,2,3,3,3,3,4,4,4,5,5,6};
__constant__ int c_i2[NPAIR] = {1,2,3,4,5,6,7,2,3,4,5,6,7,3,4,5,6,7,4,5,6,7,5,6,7,6,7,7};

// B[n][k]: k=0 -> DC (1/1024); k=1 -> Nyquist ((-1)^n/1024); k=2b -> 2cos/1024, 2b+1 -> -2sin/1024
__global__ void init_btw() {
    int idx = blockIdx.x * 256 + threadIdx.x;
    int n = idx >> 10, k = idx & 1023;
    float v;
    if (k == 0)      v = 1.0f / 1024.0f;
    else if (k == 1) v = (n & 1) ? (-1.0f / 1024.0f) : (1.0f / 1024.0f);
    else {
        int bin = k >> 1, tau = n - 32;
        int r = (tau * bin) & 1023;
        float ang = (float)r * (6.283185307179586f / 1024.0f);
        float s, c; sincosf(ang, &s, &c);
        v = ((k & 1) ? -s : c) * (2.0f / 1024.0f);
    }
    g_Btw[idx] = (_Float16)v;
}

// Bijective XOR swizzle (no padding), verified rounds 1-4 (absmax identical).
#define PHI(i) ((i) ^ (((i) >> 4) & 15) ^ ((((i) >> 8) & 3) << 1))

__device__ inline float2 cmul(float2 a, float2 b) {
    return make_float2(fmaf(a.x, b.x, -a.y * b.y), fmaf(a.x, b.y, a.y * b.x));
}
__device__ inline float2 cadd(float2 a, float2 b) { return make_float2(a.x + b.x, a.y + b.y); }
__device__ inline float2 csub(float2 a, float2 b) { return make_float2(a.x - b.x, a.y - b.y); }
__device__ inline float2 cmni(float2 a) { return make_float2(a.y, -a.x); }  // a * (-i)

// DIF 8-point DFT: y_k = sum_r v_r W8^{rk}, in place
__device__ inline void dft8(float2 v[8]) {
    const float rt = 0.70710678118654752440f;
    float2 b0 = cadd(v[0], v[4]), b1 = cadd(v[1], v[5]);
    float2 b2 = cadd(v[2], v[6]), b3 = cadd(v[3], v[7]);
    float2 c0 = csub(v[0], v[4]);
    float2 t1 = csub(v[1], v[5]);
    float2 c1 = make_float2(rt * (t1.x + t1.y), rt * (t1.y - t1.x));   // *W8^1
    float2 c2 = cmni(csub(v[2], v[6]));                                 // *W8^2
    float2 t3 = csub(v[3], v[7]);
    float2 c3 = make_float2(rt * (t3.y - t3.x), -rt * (t3.x + t3.y));  // *W8^3
    float2 f0 = cadd(b0, b2), f1 = cadd(b1, b3);
    float2 g0 = csub(b0, b2), g1 = cmni(csub(b1, b3));
    v[0] = cadd(f0, f1); v[4] = csub(f0, f1);
    v[2] = cadd(g0, g1); v[6] = csub(g0, g1);
    f0 = cadd(c0, c2); f1 = cadd(c1, c3);
    g0 = csub(c0, c2); g1 = cmni(csub(c1, c3));
    v[1] = cadd(f0, f1); v[5] = csub(f0, f1);
    v[3] = cadd(g0, g1); v[7] = csub(g0, g1);
}

// twiddle powers as a depth-3 tree
__device__ inline void twiddle8(float2 v[8], float2 w1) {
    float2 w2 = cmul(w1, w1);
    float2 w3 = cmul(w2, w1);
    float2 w4 = cmul(w2, w2);
    float2 w5 = cmul(w4, w1);
    float2 w6 = cmul(w4, w2);
    float2 w7 = cmul(w4, w3);
    v[1] = cmul(v[1], w1); v[2] = cmul(v[2], w2); v[3] = cmul(v[3], w3);
    v[4] = cmul(v[4], w4); v[5] = cmul(v[5], w5); v[6] = cmul(v[6], w6);
    v[7] = cmul(v[7], w7);
}

// DIF radices (2,8,8,8): X[k] sits at p(k)
__device__ inline int posmap(int k) {
    return ((k & 1) << 9) | (((k >> 1) & 7) << 6) | (((k >> 4) & 7) << 3) | ((k >> 7) & 7);
}

// LDS union: FFT workspace (32768 B) overlaps {fp16 spectra sX (16512 B) + A tile (16896 B)}.
// sX/A writes begin only after ALL s_z reads complete (barrier-separated).
union SMem {
    float2 z[4 * 1024];                      // 32768 B
    struct {
        _Float16 X[2 * XPLANE];              // 16512 B: [plane][bin][4 x half2]
        _Float16 A[32 * APITCH];             // 16896 B
    } p;
};                                           // sizeof = 33408 B -> 4 blocks/CU

__global__ __launch_bounds__(512, 4) void gcc_main(const float* __restrict__ x,
                                                   float* __restrict__ out) {
    __shared__ __align__(16) SMem sm;

    const int tid = threadIdx.x;
    const int t = blockIdx.x, b = blockIdx.y;
    const int f = tid & 127, c = tid >> 7;
    float2* Zb = sm.z + c * 1024;

    // per-thread base twiddle w = W_1024^f
    float ws, wc;
    sincosf((float)f * (-6.283185307179586f / 1024.0f), &ws, &wc);
    const float2 w = make_float2(wc, ws);

    // ---- fused global load + radix-2 stage (stride 512) ----
    {
        const float* xa = x + (((size_t)b * M_ + 2 * c) * T_ + t) * L_;
        const float* xb = xa + (size_t)T_ * L_;
        float va[8], vb[8];
#pragma unroll
        for (int j = 0; j < 8; ++j) { va[j] = xa[f + 128 * j]; vb[j] = xb[f + 128 * j]; }
        const float rt = 0.70710678118654752440f;
#pragma unroll
        for (int q = 0; q < 4; ++q) {
            float2 a = make_float2(va[q], vb[q]);
            float2 d = make_float2(va[q + 4], vb[q + 4]);
            float2 tq = cmul(csub(a, d), w);
            float2 r;
            if (q == 0)      r = tq;                                            // *W8^0
            else if (q == 1) r = make_float2(rt * (tq.x + tq.y), rt * (tq.y - tq.x));   // *W8^1
            else if (q == 2) r = make_float2(tq.y, -tq.x);                      // *W8^2
            else             r = make_float2(rt * (tq.y - tq.x), -rt * (tq.x + tq.y)); // *W8^3
            Zb[PHI(f + 128 * q)]       = cadd(a, d);
            Zb[PHI(f + 128 * q + 512)] = r;
        }
    }
    __syncthreads();

    // ---- Stage B: radix-8, stride 64 ----
    {
        float2 wl = w;
        if (f & 64) wl = cmul(wl, make_float2(0.92387953251128674f, 0.38268343236508977f));
        const float2 wB = cmul(wl, wl);   // = W_1024^{2*(f&63)}
        const int base = (f >> 6) * 512 + (f & 63);
        float2 v[8];
#pragma unroll
        for (int r = 0; r < 8; ++r) v[r] = Zb[PHI(base + 64 * r)];
        dft8(v);
        twiddle8(v, wB);
#pragma unroll
        for (int k = 0; k < 8; ++k) Zb[PHI(base + 64 * k)] = v[k];
    }
    __syncthreads();

    // ---- Stage C: radix-8, stride 8 ----
    {
        float s2, c2;
        sincosf((float)(f & 7) * (-6.283185307179586f / 64.0f), &s2, &c2);  // W_1024^{16*(f&7)}
        const float2 wC = make_float2(c2, s2);
        const int base = (f >> 3) * 64 + (f & 7);
        float2 v[8];
#pragma unroll
        for (int r = 0; r < 8; ++r) v[r] = Zb[PHI(base + 8 * r)];
        dft8(v);
        twiddle8(v, wC);
#pragma unroll
        for (int k = 0; k < 8; ++k) Zb[PHI(base + 8 * k)] = v[k];
    }
    __syncthreads();

    // ---- Stage D: radix-8, stride 1 (no twiddle) ----
    {
        const int base = f * 8;
        float2 v[8];
#pragma unroll
        for (int r = 0; r < 8; ++r) v[r] = Zb[PHI(base + r)];
        dft8(v);
#pragma unroll
        for (int k = 0; k < 8; ++k) Zb[PHI(base + k)] = v[k];
    }
    __syncthreads();

    // ---- One-shot unpack: thread tid -> bin tid (all 8 channels) -> fp16 sX ----
    // Stores 2*X (PHAT is scale-invariant). Read-all -> barrier -> write-in-place.
    {
        const int k = tid;                       // 0..511
        const int pa = posmap(k);
        const int pb = posmap((1024 - k) & 1023);
        float2 Z8[8];
#pragma unroll
        for (int cc = 0; cc < 4; ++cc) {
            Z8[2 * cc]     = sm.z[cc * 1024 + PHI(pa)];
            Z8[2 * cc + 1] = sm.z[cc * 1024 + PHI(pb)];
        }
        float2 ny0 = make_float2(0.f, 0.f), ny1 = ny0, ny2 = ny0, ny3 = ny0;
        if (tid == 0) {                          // Nyquist slots, PHI(posmap(512)) == 4
            ny0 = sm.z[0 * 1024 + 4]; ny1 = sm.z[1 * 1024 + 4];
            ny2 = sm.z[2 * 1024 + 4]; ny3 = sm.z[3 * 1024 + 4];
        }
        __syncthreads();                         // ALL z reads complete

        half8 lo, hi;
#pragma unroll
        for (int cc = 0; cc < 4; ++cc) {
            float2 Aa = Z8[2 * cc], Bb = Z8[2 * cc + 1];
            float xr = Aa.x + Bb.x, xi = Aa.y - Bb.y;    // 2*X_{2cc}
            float yr = Aa.y + Bb.y, yi = Bb.x - Aa.x;    // 2*X_{2cc+1}
            const int o = (cc & 1) * 4;
            if (cc < 2) {
                lo[o + 0] = (_Float16)xr; lo[o + 1] = (_Float16)xi;
                lo[o + 2] = (_Float16)yr; lo[o + 3] = (_Float16)yi;
            } else {
                hi[o + 0] = (_Float16)xr; hi[o + 1] = (_Float16)xi;
                hi[o + 2] = (_Float16)yr; hi[o + 3] = (_Float16)yi;
            }
        }
        *(half8*)(sm.p.X + 0 * XPLANE + k * 8) = lo;
        *(half8*)(sm.p.X + 1 * XPLANE + k * 8) = hi;
        if (tid == 0) {                          // bin 512: reals only (imag = 0)
            half8 nlo, nhi;
            nlo[0] = (_Float16)ny0.x; nlo[1] = (_Float16)0.f;
            nlo[2] = (_Float16)ny0.y; nlo[3] = (_Float16)0.f;
            nlo[4] = (_Float16)ny1.x; nlo[5] = (_Float16)0.f;
            nlo[6] = (_Float16)ny1.y; nlo[7] = (_Float16)0.f;
            nhi[0] = (_Float16)ny2.x; nhi[1] = (_Float16)0.f;
            nhi[2] = (_Float16)ny2.y; nhi[3] = (_Float16)0.f;
            nhi[4] = (_Float16)ny3.x; nhi[5] = (_Float16)0.f;
            nhi[6] = (_Float16)ny3.y; nhi[7] = (_Float16)0.f;
            *(half8*)(sm.p.X + 0 * XPLANE + 512 * 8) = nlo;
            *(half8*)(sm.p.X + 1 * XPLANE + 512 * 8) = nhi;
        }
        __syncthreads();                         // sX ready; z fully dead
    }

    // ---- Phases 2+3: round-0 back half, fill reads dense fp16 sX ----
    const int lane = tid & 63, wv = tid >> 6;
    const int mt = wv >> 2, nt = wv & 3;
    const int l15 = lane & 15, quad = lane >> 4;
    const int arow = mt * 16 + l15;
    const _Float16* Bbase = g_Btw + (nt * 16 + l15) * KTOT;
    floatx4 acc = {0.0f, 0.0f, 0.0f, 0.0f};

    const int bl = tid & 127, pg = tid >> 7;     // (bin-local, pair-group of 7)

#define PAIRA(p_, a_, b_)                                                     \
    {                                                                         \
        float2 X1 = Xs[a_], X2 = Xs[b_];                                      \
        float rr = X1.x * X2.x + X1.y * X2.y;                                 \
        float ri = X1.y * X2.x - X1.x * X2.y;                                 \
        float m2 = rr * rr + ri * ri;                                         \
        float inv = (m2 > 1e-30f) ? rsqrtf(m2) : 0.0f;                        \
        *(half2t*)&sm.p.A[(p_) * APITCH + 2 * bl] =                           \
            (half2t){(_Float16)(rr * inv), (_Float16)(ri * inv)};             \
    }

    auto fillA = [&](int h) {
        const int bin = h * 128 + bl;
        half8 lo = *(const half8*)(sm.p.X + 0 * XPLANE + bin * 8);  // ch 0..3
        half8 hi = *(const half8*)(sm.p.X + 1 * XPLANE + bin * 8);  // ch 4..7
        float2 Xs[8];
#pragma unroll
        for (int ch = 0; ch < 4; ++ch) {
            Xs[ch]     = make_float2((float)lo[2 * ch], (float)lo[2 * ch + 1]);
            Xs[4 + ch] = make_float2((float)hi[2 * ch], (float)hi[2 * ch + 1]);
        }
        // pg is wave-uniform (tid>>7): 4-way uniform branch, literal indices
        if (pg == 0) {
            PAIRA(0, 0, 1) PAIRA(1, 0, 2) PAIRA(2, 0, 3) PAIRA(3, 0, 4)
            PAIRA(4, 0, 5) PAIRA(5, 0, 6) PAIRA(6, 0, 7)
        } else if (pg == 1) {
            PAIRA(7, 1, 2) PAIRA(8, 1, 3) PAIRA(9, 1, 4) PAIRA(10, 1, 5)
            PAIRA(11, 1, 6) PAIRA(12, 1, 7) PAIRA(13, 2, 3)
        } else if (pg == 2) {
            PAIRA(14, 2, 4) PAIRA(15, 2, 5) PAIRA(16, 2, 6) PAIRA(17, 2, 7)
            PAIRA(18, 3, 4) PAIRA(19, 3, 5) PAIRA(20, 3, 6)
        } else {
            PAIRA(21, 3, 7) PAIRA(22, 4, 5) PAIRA(23, 4, 6) PAIRA(24, 4, 7)
            PAIRA(25, 5, 6) PAIRA(26, 5, 7) PAIRA(27, 6, 7)
        }
        if (h == 0 && bl == 0) {                 // Nyquist -> hijacked col k=1 (sign-only)
#pragma unroll
            for (int pp = 0; pp < 7; ++pp) {
                const int p = pg * 7 + pp;
                const int ca = c_i1[p], cb = c_i2[p];
                float x1 = (float)sm.p.X[(ca >> 2) * XPLANE + 512 * 8 + (ca & 3) * 2];
                float x2 = (float)sm.p.X[(cb >> 2) * XPLANE + 512 * 8 + (cb & 3) * 2];
                float rr = x1 * x2;
                float inv = (rr * rr > 1e-30f) ? rsqrtf(rr * rr) : 0.0f;
                sm.p.A[p * APITCH + 1] = (_Float16)(rr * inv);
            }
        }
    };

    for (int h = 0; h < NCHUNK; ++h) {
        fillA(h);
        __syncthreads();

        const _Float16* Ap = sm.p.A + arow * APITCH;
        const _Float16* Bp = Bbase + h * CH_K;
#pragma unroll
        for (int kt = 0; kt < NKT; ++kt) {
            half8 af = *(const half8*)(Ap + kt * 32 + quad * 8);
            half8 bf = *(const half8*)(Bp + kt * 32 + quad * 8);
            acc = __builtin_amdgcn_mfma_f32_16x16x32_f16(af, bf, acc, 0, 0, 0);
        }
        __syncthreads();
    }

    // ---- Epilogue: C/D layout col=lane&15, row=quad*4+reg ----
#pragma unroll
    for (int r = 0; r < 4; ++r) {
        int pair = mt * 16 + quad * 4 + r;
        if (pair < NPAIR)
            out[((((size_t)b * NPAIR + pair) * T_ + t) << 6) + nt * 16 + l15] = acc[r];
    }
}

extern "C" void kernel_launch(void* const* d_in, const int* in_sizes, int n_in,
                              void* d_out, int out_size, void* d_ws, size_t ws_size,
                              hipStream_t stream) {
    (void)in_sizes; (void)n_in; (void)d_ws; (void)ws_size; (void)out_size;
    hipLaunchKernelGGL(init_btw, dim3(256), dim3(256), 0, stream);
    hipLaunchKernelGGL(gcc_main, dim3(T_, B_), dim3(512), 0, stream,
                       (const float*)d_in[0], (float*)d_out);
}

// Round 6
// 287.004 us; speedup vs baseline: 1.3003x; 1.0045x over previous
//
#include <hip/hip_runtime.h>
#include <math.h>

#define B_    16
#define M_    8
#define T_    250
#define L_    1024
#define NPAIR 28

#define KTOT   1024
#define CH_K   256      // halfs per chunk (128 bins)
#define NKT    8
#define NCHUNK 4
#define APITCH 264      // 256 + 8 halfs pad; row stride 528 B (16B multiple)
#define XPLANE (516 * 8)   // halfs per fp16-spectrum plane (8256 B)

typedef _Float16 half8  __attribute__((ext_vector_type(8)));
typedef _Float16 half2t __attribute__((ext_vector_type(2)));
typedef float    floatx4 __attribute__((ext_vector_type(4)));

__device__ __align__(16) _Float16 g_Btw[64 * KTOT];

// np.triu_indices(8, k=1) — used only by the Nyquist fixup
__constant__ int c_i1[NPAIR] = {0,0,0,0,0,0,0,1,1,1,1,1,1,2,2,2,2,2,3,3,3,3,4,4,4,5,5,6};
__constant__ int c_i2[NPAIR] = {1,2,3,4,5,6,7,2,3,4,5,6,7,3,4,5,6,7,4,5,6,7,5,6,7,6,7,7};

// B[n][k]: k=0 -> DC (1/1024); k=1 -> Nyquist ((-1)^n/1024); k=2b -> 2cos/1024, 2b+1 -> -2sin/1024
__global__ void init_btw() {
    int idx = blockIdx.x * 256 + threadIdx.x;
    int n = idx >> 10, k = idx & 1023;
    float v;
    if (k == 0)      v = 1.0f / 1024.0f;
    else if (k == 1) v = (n & 1) ? (-1.0f / 1024.0f) : (1.0f / 1024.0f);
    else {
        int bin = k >> 1, tau = n - 32;
        int r = (tau * bin) & 1023;
        float ang = (float)r * (6.283185307179586f / 1024.0f);
        float s, c; sincosf(ang, &s, &c);
        v = ((k & 1) ? -s : c) * (2.0f / 1024.0f);
    }
    g_Btw[idx] = (_Float16)v;
}

// Bijective XOR swizzle (no padding), verified rounds 1-5 (absmax identical).
#define PHI(i) ((i) ^ (((i) >> 4) & 15) ^ ((((i) >> 8) & 3) << 1))

__device__ inline float2 cmul(float2 a, float2 b) {
    return make_float2(fmaf(a.x, b.x, -a.y * b.y), fmaf(a.x, b.y, a.y * b.x));
}
__device__ inline float2 cadd(float2 a, float2 b) { return make_float2(a.x + b.x, a.y + b.y); }
__device__ inline float2 csub(float2 a, float2 b) { return make_float2(a.x - b.x, a.y - b.y); }
__device__ inline float2 cmni(float2 a) { return make_float2(a.y, -a.x); }  // a * (-i)

// DIF 8-point DFT: y_k = sum_r v_r W8^{rk}, in place
__device__ inline void dft8(float2 v[8]) {
    const float rt = 0.70710678118654752440f;
    float2 b0 = cadd(v[0], v[4]), b1 = cadd(v[1], v[5]);
    float2 b2 = cadd(v[2], v[6]), b3 = cadd(v[3], v[7]);
    float2 c0 = csub(v[0], v[4]);
    float2 t1 = csub(v[1], v[5]);
    float2 c1 = make_float2(rt * (t1.x + t1.y), rt * (t1.y - t1.x));   // *W8^1
    float2 c2 = cmni(csub(v[2], v[6]));                                 // *W8^2
    float2 t3 = csub(v[3], v[7]);
    float2 c3 = make_float2(rt * (t3.y - t3.x), -rt * (t3.x + t3.y));  // *W8^3
    float2 f0 = cadd(b0, b2), f1 = cadd(b1, b3);
    float2 g0 = csub(b0, b2), g1 = cmni(csub(b1, b3));
    v[0] = cadd(f0, f1); v[4] = csub(f0, f1);
    v[2] = cadd(g0, g1); v[6] = csub(g0, g1);
    f0 = cadd(c0, c2); f1 = cadd(c1, c3);
    g0 = csub(c0, c2); g1 = cmni(csub(c1, c3));
    v[1] = cadd(f0, f1); v[5] = csub(f0, f1);
    v[3] = cadd(g0, g1); v[7] = csub(g0, g1);
}

// twiddle powers as a depth-3 tree
__device__ inline void twiddle8(float2 v[8], float2 w1) {
    float2 w2 = cmul(w1, w1);
    float2 w3 = cmul(w2, w1);
    float2 w4 = cmul(w2, w2);
    float2 w5 = cmul(w4, w1);
    float2 w6 = cmul(w4, w2);
    float2 w7 = cmul(w4, w3);
    v[1] = cmul(v[1], w1); v[2] = cmul(v[2], w2); v[3] = cmul(v[3], w3);
    v[4] = cmul(v[4], w4); v[5] = cmul(v[5], w5); v[6] = cmul(v[6], w6);
    v[7] = cmul(v[7], w7);
}

// DIF radices (2,8,8,8): X[k] sits at p(k)
__device__ inline int posmap(int k) {
    return ((k & 1) << 9) | (((k >> 1) & 7) << 6) | (((k >> 4) & 7) << 3) | ((k >> 7) & 7);
}

// LDS union: FFT workspace (32768 B) overlaps {fp16 unit-spectra sX (16512 B) + A tile (16896 B)}.
// sX/A writes begin only after ALL s_z reads complete (barrier-separated).
union SMem {
    float2 z[4 * 1024];                      // 32768 B
    struct {
        _Float16 X[2 * XPLANE];              // 16512 B: [plane][bin][4 x half2] (unit vectors)
        _Float16 A[32 * APITCH];             // 16896 B
    } p;
};                                           // sizeof = 33408 B -> 4 blocks/CU

__global__ __launch_bounds__(512, 4) void gcc_main(const float* __restrict__ x,
                                                   float* __restrict__ out) {
    __shared__ __align__(16) SMem sm;

    const int tid = threadIdx.x;
    const int t = blockIdx.x, b = blockIdx.y;
    const int f = tid & 127, c = tid >> 7;
    float2* Zb = sm.z + c * 1024;

    // per-thread base twiddle w = W_1024^f
    float ws, wc;
    sincosf((float)f * (-6.283185307179586f / 1024.0f), &ws, &wc);
    const float2 w = make_float2(wc, ws);

    // ---- fused global load + radix-2 stage (stride 512) ----
    {
        const float* xa = x + (((size_t)b * M_ + 2 * c) * T_ + t) * L_;
        const float* xb = xa + (size_t)T_ * L_;
        float va[8], vb[8];
#pragma unroll
        for (int j = 0; j < 8; ++j) { va[j] = xa[f + 128 * j]; vb[j] = xb[f + 128 * j]; }
        const float rt = 0.70710678118654752440f;
#pragma unroll
        for (int q = 0; q < 4; ++q) {
            float2 a = make_float2(va[q], vb[q]);
            float2 d = make_float2(va[q + 4], vb[q + 4]);
            float2 tq = cmul(csub(a, d), w);
            float2 r;
            if (q == 0)      r = tq;                                            // *W8^0
            else if (q == 1) r = make_float2(rt * (tq.x + tq.y), rt * (tq.y - tq.x));   // *W8^1
            else if (q == 2) r = make_float2(tq.y, -tq.x);                      // *W8^2
            else             r = make_float2(rt * (tq.y - tq.x), -rt * (tq.x + tq.y)); // *W8^3
            Zb[PHI(f + 128 * q)]       = cadd(a, d);
            Zb[PHI(f + 128 * q + 512)] = r;
        }
    }
    __syncthreads();

    // ---- Stage B: radix-8, stride 64 ----
    {
        float2 wl = w;
        if (f & 64) wl = cmul(wl, make_float2(0.92387953251128674f, 0.38268343236508977f));
        const float2 wB = cmul(wl, wl);   // = W_1024^{2*(f&63)}
        const int base = (f >> 6) * 512 + (f & 63);
        float2 v[8];
#pragma unroll
        for (int r = 0; r < 8; ++r) v[r] = Zb[PHI(base + 64 * r)];
        dft8(v);
        twiddle8(v, wB);
#pragma unroll
        for (int k = 0; k < 8; ++k) Zb[PHI(base + 64 * k)] = v[k];
    }
    __syncthreads();

    // ---- Stage C: radix-8, stride 8 ----
    {
        float s2, c2;
        sincosf((float)(f & 7) * (-6.283185307179586f / 64.0f), &s2, &c2);  // W_1024^{16*(f&7)}
        const float2 wC = make_float2(c2, s2);
        const int base = (f >> 3) * 64 + (f & 7);
        float2 v[8];
#pragma unroll
        for (int r = 0; r < 8; ++r) v[r] = Zb[PHI(base + 8 * r)];
        dft8(v);
        twiddle8(v, wC);
#pragma unroll
        for (int k = 0; k < 8; ++k) Zb[PHI(base + 8 * k)] = v[k];
    }
    __syncthreads();

    // ---- Stage D: radix-8, stride 1 (no twiddle) ----
    {
        const int base = f * 8;
        float2 v[8];
#pragma unroll
        for (int r = 0; r < 8; ++r) v[r] = Zb[PHI(base + r)];
        dft8(v);
#pragma unroll
        for (int k = 0; k < 8; ++k) Zb[PHI(base + k)] = v[k];
    }
    __syncthreads();

    // ---- One-shot unpack + PER-CHANNEL PHAT normalize -> fp16 unit vectors sX ----
    // R/|R| = (X1/|X1|) * conj(X2/|X2|): normalization factorizes per channel.
    // 8 rsqrt here replace 28 per-pair rsqrt+guard+m2 in fill.
    {
        const int k = tid;                       // 0..511
        const int pa = posmap(k);
        const int pb = posmap((1024 - k) & 1023);
        float2 Z8[8];
#pragma unroll
        for (int cc = 0; cc < 4; ++cc) {
            Z8[2 * cc]     = sm.z[cc * 1024 + PHI(pa)];
            Z8[2 * cc + 1] = sm.z[cc * 1024 + PHI(pb)];
        }
        float2 ny0 = make_float2(0.f, 0.f), ny1 = ny0, ny2 = ny0, ny3 = ny0;
        if (tid == 0) {                          // Nyquist slots, PHI(posmap(512)) == 4
            ny0 = sm.z[0 * 1024 + 4]; ny1 = sm.z[1 * 1024 + 4];
            ny2 = sm.z[2 * 1024 + 4]; ny3 = sm.z[3 * 1024 + 4];
        }
        __syncthreads();                         // ALL z reads complete

        half8 lo, hi;
#pragma unroll
        for (int cc = 0; cc < 4; ++cc) {
            float2 Aa = Z8[2 * cc], Bb = Z8[2 * cc + 1];
            float xr = Aa.x + Bb.x, xi = Aa.y - Bb.y;    // ~2*X_{2cc} (scale dropped: PHAT)
            float yr = Aa.y + Bb.y, yi = Bb.x - Aa.x;    // ~2*X_{2cc+1}
            float mx = fmaf(xr, xr, xi * xi);
            float ix = (mx > 1e-30f) ? rsqrtf(mx) : 0.0f;
            float my = fmaf(yr, yr, yi * yi);
            float iy = (my > 1e-30f) ? rsqrtf(my) : 0.0f;
            xr *= ix; xi *= ix; yr *= iy; yi *= iy;
            const int o = (cc & 1) * 4;
            if (cc < 2) {
                lo[o + 0] = (_Float16)xr; lo[o + 1] = (_Float16)xi;
                lo[o + 2] = (_Float16)yr; lo[o + 3] = (_Float16)yi;
            } else {
                hi[o + 0] = (_Float16)xr; hi[o + 1] = (_Float16)xi;
                hi[o + 2] = (_Float16)yr; hi[o + 3] = (_Float16)yi;
            }
        }
        *(half8*)(sm.p.X + 0 * XPLANE + k * 8) = lo;
        *(half8*)(sm.p.X + 1 * XPLANE + k * 8) = hi;
        if (tid == 0) {                          // bin 512: u = sign(X) in {+1,-1,0}, imag 0
            half8 nlo, nhi;
#define SGN(s_) ((_Float16)(((s_) * (s_) > 1e-30f) ? copysignf(1.0f, (s_)) : 0.0f))
            nlo[0] = SGN(ny0.x); nlo[1] = (_Float16)0.f;
            nlo[2] = SGN(ny0.y); nlo[3] = (_Float16)0.f;
            nlo[4] = SGN(ny1.x); nlo[5] = (_Float16)0.f;
            nlo[6] = SGN(ny1.y); nlo[7] = (_Float16)0.f;
            nhi[0] = SGN(ny2.x); nhi[1] = (_Float16)0.f;
            nhi[2] = SGN(ny2.y); nhi[3] = (_Float16)0.f;
            nhi[4] = SGN(ny3.x); nhi[5] = (_Float16)0.f;
            nhi[6] = SGN(ny3.y); nhi[7] = (_Float16)0.f;
#undef SGN
            *(half8*)(sm.p.X + 0 * XPLANE + 512 * 8) = nlo;
            *(half8*)(sm.p.X + 1 * XPLANE + 512 * 8) = nhi;
        }
        __syncthreads();                         // sX ready; z fully dead
    }

    // ---- Phases 2+3: fill is now a pure cmul per pair (no per-pair rsqrt) ----
    const int lane = tid & 63, wv = tid >> 6;
    const int mt = wv >> 2, nt = wv & 3;
    const int l15 = lane & 15, quad = lane >> 4;
    const int arow = mt * 16 + l15;
    const _Float16* Bbase = g_Btw + (nt * 16 + l15) * KTOT;
    floatx4 acc = {0.0f, 0.0f, 0.0f, 0.0f};

    const int bl = tid & 127, pg = tid >> 7;     // (bin-local, pair-group of 7)

#define PAIRA(p_, a_, b_)                                                     \
    {                                                                         \
        float2 U1 = Xs[a_], U2 = Xs[b_];                                      \
        float rr = fmaf(U1.x, U2.x, U1.y * U2.y);                             \
        float ri = fmaf(U1.y, U2.x, -U1.x * U2.y);                            \
        *(half2t*)&sm.p.A[(p_) * APITCH + 2 * bl] =                           \
            (half2t){(_Float16)rr, (_Float16)ri};                             \
    }

    auto fillA = [&](int h) {
        const int bin = h * 128 + bl;
        half8 lo = *(const half8*)(sm.p.X + 0 * XPLANE + bin * 8);  // ch 0..3
        half8 hi = *(const half8*)(sm.p.X + 1 * XPLANE + bin * 8);  // ch 4..7
        float2 Xs[8];
#pragma unroll
        for (int ch = 0; ch < 4; ++ch) {
            Xs[ch]     = make_float2((float)lo[2 * ch], (float)lo[2 * ch + 1]);
            Xs[4 + ch] = make_float2((float)hi[2 * ch], (float)hi[2 * ch + 1]);
        }
        // pg is wave-uniform (tid>>7): 4-way uniform branch, literal indices
        if (pg == 0) {
            PAIRA(0, 0, 1) PAIRA(1, 0, 2) PAIRA(2, 0, 3) PAIRA(3, 0, 4)
            PAIRA(4, 0, 5) PAIRA(5, 0, 6) PAIRA(6, 0, 7)
        } else if (pg == 1) {
            PAIRA(7, 1, 2) PAIRA(8, 1, 3) PAIRA(9, 1, 4) PAIRA(10, 1, 5)
            PAIRA(11, 1, 6) PAIRA(12, 1, 7) PAIRA(13, 2, 3)
        } else if (pg == 2) {
            PAIRA(14, 2, 4) PAIRA(15, 2, 5) PAIRA(16, 2, 6) PAIRA(17, 2, 7)
            PAIRA(18, 3, 4) PAIRA(19, 3, 5) PAIRA(20, 3, 6)
        } else {
            PAIRA(21, 3, 7) PAIRA(22, 4, 5) PAIRA(23, 4, 6) PAIRA(24, 4, 7)
            PAIRA(25, 5, 6) PAIRA(26, 5, 7) PAIRA(27, 6, 7)
        }
        if (h == 0 && bl == 0) {                 // Nyquist -> hijacked col k=1: sign product
#pragma unroll
            for (int pp = 0; pp < 7; ++pp) {
                const int p = pg * 7 + pp;
                const int ca = c_i1[p], cb = c_i2[p];
                float x1 = (float)sm.p.X[(ca >> 2) * XPLANE + 512 * 8 + (ca & 3) * 2];
                float x2 = (float)sm.p.X[(cb >> 2) * XPLANE + 512 * 8 + (cb & 3) * 2];
                sm.p.A[p * APITCH + 1] = (_Float16)(x1 * x2);
            }
        }
    };

    for (int h = 0; h < NCHUNK; ++h) {
        fillA(h);
        __syncthreads();

        // explicit software pipeline: A(kt+1)/B(kt+1) in flight during MFMA(kt)
        const _Float16* Ap = sm.p.A + arow * APITCH + quad * 8;
        const _Float16* Bp = Bbase + h * CH_K + quad * 8;
        half8 af = *(const half8*)(Ap);
        half8 bf = *(const half8*)(Bp);
#pragma unroll
        for (int kt = 0; kt < NKT; ++kt) {
            half8 an = af, bn = bf;
            if (kt + 1 < NKT) {
                an = *(const half8*)(Ap + (kt + 1) * 32);
                bn = *(const half8*)(Bp + (kt + 1) * 32);
            }
            acc = __builtin_amdgcn_mfma_f32_16x16x32_f16(af, bf, acc, 0, 0, 0);
            af = an; bf = bn;
        }
        __syncthreads();
    }

    // ---- Epilogue: C/D layout col=lane&15, row=quad*4+reg ----
#pragma unroll
    for (int r = 0; r < 4; ++r) {
        int pair = mt * 16 + quad * 4 + r;
        if (pair < NPAIR)
            out[((((size_t)b * NPAIR + pair) * T_ + t) << 6) + nt * 16 + l15] = acc[r];
    }
}

extern "C" void kernel_launch(void* const* d_in, const int* in_sizes, int n_in,
                              void* d_out, int out_size, void* d_ws, size_t ws_size,
                              hipStream_t stream) {
    (void)in_sizes; (void)n_in; (void)d_ws; (void)ws_size; (void)out_size;
    hipLaunchKernelGGL(init_btw, dim3(256), dim3(256), 0, stream);
    hipLaunchKernelGGL(gcc_main, dim3(T_, B_), dim3(512), 0, stream,
                       (const float*)d_in[0], (float*)d_out);
}